// Round 12
// baseline (186.819 us; speedup 1.0000x reference)
//
#include <hip/hip_runtime.h>
#include <hip/hip_bf16.h>

// Problem constants: B=4, C=64, H=256, W=448, fp32.
#define BB 4
#define CC 64
#define HH 256
#define WW 448
constexpr int HW  = HH * WW;    // 114688
constexpr int CHW = CC * HW;    // 7340032

// Gather-tile geometry
#define TX 32                   // tile width  (W=448 -> 14 tiles)
#define TY 8                    // tile height (H=256 -> 32 tiles)
#define NTX (WW / TX)           // 14
#define NTY (HH / TY)           // 32
#define NWG (NTX * NTY * BB)    // 1792 (divisible by 8 XCDs)
#define TH 7                    // halo; "local" iff |d| <= 6
#define LOCAL_MAX 6.0f
#define WINX (TX + 2*TH)        // 46
#define WINY (TY + 2*TH)        // 22
#define NSRC (WINX * WINY)      // 1012
#define TPB 256
#define MAXK 4                  // ceil(NSRC/TPB)
#define NCH 16                  // channels per chunk (bf16-staged)
#define NCHUNK (CC / NCH)       // 4 chunks, looped INSIDE the block
#define NCELLX (TX + 1)         // 33  (cells lx = -1..TX-1)
#define NCELLY (TY + 1)         // 9
#define NCELL (NCELLX * NCELLY) // 297
#define CAPC 8                  // per-cell list capacity (Poisson(1): P(>8)~1e-6)
#define CAP 448                 // compact-id capacity (mean ~330, +8 sigma)
#define OVCAP 64                // overflow side-list capacity

// pack two fp32 -> one u32 of 2x bf16 (RNE); lo -> bits[15:0], hi -> bits[31:16]
__device__ __forceinline__ unsigned pack_bf16(float lo, float hi) {
    __hip_bfloat162 h = __float22bfloat162_rn(float2{lo, hi});
    return *reinterpret_cast<unsigned*>(&h);
}

// ws layout (floats): [0, B*HW) = weight accumulator (outliers only);
//                     [B*HW]    = outlier flag (as u32)

// ---------------------------------------------------------------------------
// K1: detect any source pixel with |flow| > LOCAL_MAX (rare path trigger).
// ---------------------------------------------------------------------------
__global__ __launch_bounds__(TPB) void flag_kernel(
    const float* __restrict__ flow, unsigned* __restrict__ flag)
{
    int p = blockIdx.x * TPB + threadIdx.x;
    if (p >= BB * HW) return;
    int b = p / HW, rem = p - b * HW;
    float dx = flow[(b * 2 + 0) * HW + rem];
    float dy = flow[(b * 2 + 1) * HW + rem];
    if (!((fabsf(dx) <= LOCAL_MAX) && (fabsf(dy) <= LOCAL_MAX)))
        atomicOr(flag, 1u);
}

// ---------------------------------------------------------------------------
// K2: zero d_out only if outliers exist (they atomically accumulate into it).
// ---------------------------------------------------------------------------
__global__ __launch_bounds__(TPB) void cond_zero_kernel(
    float4* __restrict__ out4, const unsigned* __restrict__ flag)
{
    if (*flag == 0u) return;
    const int n4 = BB * CHW / 4;
    for (int i = blockIdx.x * TPB + threadIdx.x; i < n4; i += gridDim.x * TPB)
        out4[i] = float4{0.f, 0.f, 0.f, 0.f};
}

// ---------------------------------------------------------------------------
// K3: rare-path scatter for outlier sources (global atomics; ~0 pixels here).
// ---------------------------------------------------------------------------
__global__ __launch_bounds__(TPB) void outlier_kernel(
    const float* __restrict__ inp, const float* __restrict__ flow,
    const float* __restrict__ mask, float* __restrict__ acc,
    float* __restrict__ wacc, const unsigned* __restrict__ flag)
{
    if (*flag == 0u) return;
    int p = blockIdx.x * TPB + threadIdx.x;
    if (p >= BB * HW) return;
    int b = p / HW, rem = p - b * HW;
    int y = rem / WW, x = rem - y * WW;

    float dx = flow[(b * 2 + 0) * HW + rem];
    float dy = flow[(b * 2 + 1) * HW + rem];
    if ((fabsf(dx) <= LOCAL_MAX) && (fabsf(dy) <= LOCAL_MAX)) return;

    float tx = (float)x + dx, ty = (float)y + dy;
    float x0f = floorf(tx), y0f = floorf(ty);
    int   x0 = (int)x0f, y0 = (int)y0f;
    float fx = tx - x0f, fy = ty - y0f;
    float wx[2] = {1.0f - fx, fx};
    float wy[2] = {1.0f - fy, fy};
    float m = expf(mask[b * HW + rem]);

    int   cidx[4];
    float cw[4];
    bool  cv[4];
#pragma unroll
    for (int j = 0; j < 4; ++j) {
        int xi = x0 + (j & 1), yi = y0 + (j >> 1);
        cv[j]   = (xi >= 0) & (xi < WW) & (yi >= 0) & (yi < HH);
        cidx[j] = yi * WW + xi;
        cw[j]   = wx[j & 1] * wy[j >> 1] * m;
    }
    float* wbase = wacc + b * HW;
#pragma unroll
    for (int j = 0; j < 4; ++j)
        if (cv[j]) unsafeAtomicAdd(wbase + cidx[j], cw[j]);
    const float* ibase = inp + b * CHW + rem;
    float*       obase = acc + b * CHW;
    for (int c = 0; c < CC; ++c) {
        float v = ibase[c * HW];
#pragma unroll
        for (int j = 0; j < 4; ++j)
            if (cv[j]) unsafeAtomicAdd(obase + c * HW + cidx[j], cw[j] * v);
    }
}

// ---------------------------------------------------------------------------
// K4: atomic-free gather-splat; scan/bin once per tile; channel-chunk loop
// with register prefetch; XCD-aware block swizzle; bf16 w4 + u16 slot ids
// shrink LDS to ~25 KB -> 6 blocks/CU.
// ---------------------------------------------------------------------------
__global__ __launch_bounds__(TPB, 6) void gather_kernel(
    const float* __restrict__ inp, const float* __restrict__ flow,
    const float* __restrict__ mask, float* __restrict__ out,
    const float* __restrict__ wacc, const unsigned* __restrict__ flag)
{
    __shared__ uint2          s_w4b[CAP];         // w4 as 2x (2x bf16): {j0,j1},{j2,j3}
    __shared__ unsigned short s_slot[CAP];        // window slot id (< NSRC)
    __shared__ uint4          s_vals[CAP * 2];    // 16 ch as 2xbf16 x8 (reused/chunk)
    __shared__ unsigned short s_list[NCELL * CAPC];
    __shared__ int            s_cnt[NCELL];
    __shared__ int            s_ovf[OVCAP];
    __shared__ int            s_ovfn, s_nc;

    // XCD-aware swizzle: consecutive same-XCD blocks get contiguous tile ids
    const int bid  = blockIdx.x;
    const int orig = (bid & 7) * (NWG / 8) + (bid >> 3);
    const int bxi  = orig % NTX;
    const int tmp  = orig / NTX;
    const int byi  = tmp & (NTY - 1);             // NTY = 32
    const int b    = tmp >> 5;

    const int bx0  = bxi * TX;
    const int by0  = byi * TY;
    const int tid  = threadIdx.x;
    const int lane = tid & 63;

    for (int i = tid; i < NCELL; i += TPB) s_cnt[i] = 0;
    if (tid == 0) { s_ovfn = 0; s_nc = 0; }
    __syncthreads();

    const float* __restrict__ fxp = flow + (b * 2 + 0) * HW;
    const float* __restrict__ fyp = flow + (b * 2 + 1) * HW;
    const float* __restrict__ mp  = mask + b * HW;

    // ---- Stage A: scan + compact + bin (ONCE per tile) -------------------
    for (int k = 0; k < MAXK; ++k) {
        const int s  = k * TPB + tid;
        const int sy = s / WINX;
        const int sx = s - sy * WINX;
        const int gx = bx0 - TH + sx;
        const int gy = by0 - TH + sy;
        bool pass = (s < NSRC) & (gx >= 0) & (gx < WW) & (gy >= 0) & (gy < HH);
        const int sp = gy * WW + gx;
        float dx = 0.f, dy = 0.f;
        if (pass) {
            dx = fxp[sp];
            dy = fyp[sp];
            pass = (fabsf(dx) <= LOCAL_MAX) && (fabsf(dy) <= LOCAL_MAX);
        }
        const float tx  = (float)gx + dx;
        const float ty  = (float)gy + dy;
        const float x0f = floorf(tx), y0f = floorf(ty);
        const int   lx  = (int)x0f - bx0;
        const int   ly  = (int)y0f - by0;
        pass = pass && (lx >= -1) && (lx < TX) && (ly >= -1) && (ly < TY);

        // wave-ballot compact-id allocation
        const unsigned long long ball = __ballot(pass);
        int base = 0;
        if (lane == 0) base = atomicAdd(&s_nc, (int)__popcll(ball));
        base = __shfl(base, 0);
        const int cid = base + (int)__popcll(ball & ((1ull << lane) - 1ull));

        if (!pass || cid >= CAP) continue;

        const float fx = tx - x0f, fy = ty - y0f;
        const float ox = 1.0f - fx, oy = 1.0f - fy;
        const float m  = expf(mp[sp]);
        // components ordered by jidx: {j0=ox*oy, j1=fx*oy}, {j2=ox*fy, j3=fx*fy}
        s_w4b[cid] = uint2{pack_bf16(ox * oy * m, fx * oy * m),
                           pack_bf16(ox * fy * m, fx * fy * m)};
        s_slot[cid] = (unsigned short)s;

        const int cellid = (ly + 1) * NCELLX + (lx + 1);
        const int pos = atomicAdd(&s_cnt[cellid], 1);
        if (pos < CAPC) {
            s_list[cellid * CAPC + pos] = (unsigned short)cid;
        } else {
            const int op = atomicAdd(&s_ovfn, 1);
            if (op < OVCAP) s_ovf[op] = cid | (cellid << 16);
        }
    }
    __syncthreads();

    // ---- per-pixel / per-thread constants cached across chunks -----------
    const int px = tid & 31, py = tid >> 5;        // 32x8 = 256 pixels, 1/thread
    const int c00 = min(s_cnt[(py + 0) * NCELLX + (px + 0)], CAPC);
    const int c10 = min(s_cnt[(py + 0) * NCELLX + (px + 1)], CAPC);
    const int c01 = min(s_cnt[(py + 1) * NCELLX + (px + 0)], CAPC);
    const int c11 = min(s_cnt[(py + 1) * NCELLX + (px + 1)], CAPC);
    const int t0 = c00, t1 = t0 + c10, t2 = t1 + c01, T = t2 + c11;
    const int nc   = min(s_nc, CAP);
    const int novf = min(s_ovfn, OVCAP);
    const int gpix = (by0 + py) * WW + (bx0 + px);
    const bool has_out = (*flag != 0u);
    const unsigned* __restrict__ w4w = (const unsigned*)s_w4b;

    // staging sources owned by this thread (slot -> global pixel, recomputed)
    const bool h0 = tid < nc, h1 = tid + TPB < nc;
    int sp0 = 0, sp1 = 0;
    {
        const int s0 = h0 ? (int)s_slot[tid] : 0;
        const int s1 = h1 ? (int)s_slot[tid + TPB] : 0;
        const int sy0 = s0 / WINX, sy1 = s1 / WINX;
        sp0 = (by0 - TH + sy0) * WW + (bx0 - TH + (s0 - sy0 * WINX));
        sp1 = (by0 - TH + sy1) * WW + (bx0 - TH + (s1 - sy1 * WINX));
    }

    // ---- preload chunk 0 into registers ----------------------------------
    float v0[NCH], v1[NCH];
    {
        const float* __restrict__ ib = inp + b * CC * HW;
#pragma unroll
        for (int c = 0; c < NCH; ++c) {
            v0[c] = h0 ? ib[c * HW + sp0] : 0.f;
            v1[c] = h1 ? ib[c * HW + sp1] : 0.f;
        }
    }
    unsigned pk0[8], pk1[8];
#pragma unroll
    for (int q = 0; q < 8; ++q) {
        pk0[q] = pack_bf16(v0[2 * q], v0[2 * q + 1]);
        pk1[q] = pack_bf16(v1[2 * q], v1[2 * q + 1]);
    }

    float rden = 0.f;   // set in chunk 0

    // ---- chunk loop: write LDS, prefetch next, gather, pack --------------
    for (int g = 0; g < NCHUNK; ++g) {
        if (h0) {
            s_vals[tid * 2 + 0] = uint4{pk0[0], pk0[1], pk0[2], pk0[3]};
            s_vals[tid * 2 + 1] = uint4{pk0[4], pk0[5], pk0[6], pk0[7]};
        }
        if (h1) {
            s_vals[(tid + TPB) * 2 + 0] = uint4{pk1[0], pk1[1], pk1[2], pk1[3]};
            s_vals[(tid + TPB) * 2 + 1] = uint4{pk1[4], pk1[5], pk1[6], pk1[7]};
        }
        __syncthreads();

        // issue next chunk's global loads NOW; consumed after the gather
        if (g + 1 < NCHUNK) {
            const float* __restrict__ ibn = inp + (b * CC + (g + 1) * NCH) * HW;
#pragma unroll
            for (int c = 0; c < NCH; ++c) {
                v0[c] = h0 ? ibn[c * HW + sp0] : 0.f;
                v1[c] = h1 ? ibn[c * HW + sp1] : 0.f;
            }
        }

        // ---- gather chunk g from LDS ------------------------------------
        float wsum = 0.f;
        float2 a2[8];
#pragma unroll
        for (int q = 0; q < 8; ++q) a2[q] = float2{0.f, 0.f};

        for (int k = 0; k < T; ++k) {
            int d, e, ci;
            if (k < t1) { e = 0; d = (k >= t0); ci = d ? (k - t0) : k; }
            else        { e = 1; d = (k >= t2); ci = d ? (k - t2) : (k - t1); }
            const int cellid = (py + e) * NCELLX + (px + d);
            const int cid    = s_list[cellid * CAPC + ci];
            // w component jidx = (1-d) + 2*(1-e): u32 index (1-e), hi-half if d==0
            const unsigned wb = w4w[cid * 2 + (e ^ 1)];
            const float w = __uint_as_float(d ? (wb << 16) : (wb & 0xffff0000u));
            wsum += w;
            const uint4 q0 = s_vals[cid * 2 + 0];
            const uint4 q1 = s_vals[cid * 2 + 1];
            const unsigned uu[8] = {q0.x, q0.y, q0.z, q0.w, q1.x, q1.y, q1.z, q1.w};
#pragma unroll
            for (int q = 0; q < 8; ++q) {
                a2[q].x += w * __uint_as_float(uu[q] << 16);
                a2[q].y += w * __uint_as_float(uu[q] & 0xffff0000u);
            }
        }

        // rare overflow entries (exact handling)
        for (int i = 0; i < novf; ++i) {
            const int ent    = s_ovf[i];
            const int cid    = ent & 0xffff;
            const int cellid = ent >> 16;
            const int cy = cellid / NCELLX, cx = cellid - cy * NCELLX;
            const int jx = px - (cx - 1), jy = py - (cy - 1);
            if ((unsigned)jx <= 1u && (unsigned)jy <= 1u) {
                const unsigned wb = w4w[cid * 2 + jy];
                const float w = __uint_as_float(jx ? (wb & 0xffff0000u) : (wb << 16));
                wsum += w;
                const uint4 q0 = s_vals[cid * 2 + 0];
                const uint4 q1 = s_vals[cid * 2 + 1];
                const unsigned uu[8] = {q0.x, q0.y, q0.z, q0.w, q1.x, q1.y, q1.z, q1.w};
#pragma unroll
                for (int q = 0; q < 8; ++q) {
                    a2[q].x += w * __uint_as_float(uu[q] << 16);
                    a2[q].y += w * __uint_as_float(uu[q] & 0xffff0000u);
                }
            }
        }

        if (g == 0)
            rden = 1.0f / (wsum + wacc[b * HW + gpix] + 1e-7f);

        const int obase = (b * CC + g * NCH) * HW;
#pragma unroll
        for (int q = 0; q < 8; ++q) {
            const int gi0 = obase + (2 * q + 0) * HW + gpix;
            const int gi1 = obase + (2 * q + 1) * HW + gpix;
            float av0 = a2[q].x, av1 = a2[q].y;
            if (has_out) { av0 += out[gi0]; av1 += out[gi1]; }
            out[gi0] = av0 * rden;
            out[gi1] = av1 * rden;
        }

        // pack next chunk (vmcnt waits land here, after the gather)
        if (g + 1 < NCHUNK) {
#pragma unroll
            for (int q = 0; q < 8; ++q) {
                pk0[q] = pack_bf16(v0[2 * q], v0[2 * q + 1]);
                pk1[q] = pack_bf16(v1[2 * q], v1[2 * q + 1]);
            }
            __syncthreads();       // all gathers done before s_vals overwrite
        }
    }
}

extern "C" void kernel_launch(void* const* d_in, const int* in_sizes, int n_in,
                              void* d_out, int out_size, void* d_ws, size_t ws_size,
                              hipStream_t stream) {
    const float* inp  = (const float*)d_in[0];  // [4,64,256,448]
    const float* flow = (const float*)d_in[1];  // [4,2,256,448]
    const float* mask = (const float*)d_in[2];  // [4,1,256,448]
    float*    out  = (float*)d_out;
    float*    wacc = (float*)d_ws;                          // [B,HW] outlier weights
    unsigned* flag = (unsigned*)((float*)d_ws + BB * HW);   // outlier flag

    // zero wacc + flag every call (deterministic under graph replay)
    hipMemsetAsync(d_ws, 0, (size_t)(BB * HW + 4) * sizeof(float), stream);

    const int npix = BB * HW;
    flag_kernel<<<(npix + TPB - 1) / TPB, TPB, 0, stream>>>(flow, flag);
    cond_zero_kernel<<<2048, TPB, 0, stream>>>((float4*)out, flag);
    outlier_kernel<<<(npix + TPB - 1) / TPB, TPB, 0, stream>>>(inp, flow, mask, out, wacc, flag);
    gather_kernel<<<NWG, TPB, 0, stream>>>(inp, flow, mask, out, wacc, flag);
}

// Round 13
// 70.098 us; speedup vs baseline: 2.6651x; 2.6651x over previous
//
#include <hip/hip_runtime.h>
#include <hip/hip_bf16.h>

// Problem constants: B=4, C=64, H=256, W=448, fp32.
#define BB 4
#define CC 64
#define HH 256
#define WW 448
constexpr int HW  = HH * WW;    // 114688
constexpr int CHW = CC * HW;    // 7340032

// Gather-tile geometry
#define TX 32                   // tile width  (W=448 -> 14 tiles)
#define TY 8                    // tile height (H=256 -> 32 tiles)
#define NTX (WW / TX)           // 14
#define NTY (HH / TY)           // 32
#define NWG (NTX * NTY * BB)    // 1792 (divisible by 8 XCDs)
#define TH 7                    // halo; "local" iff |d| <= 6
#define LOCAL_MAX 6.0f
#define WINX (TX + 2*TH)        // 46
#define WINY (TY + 2*TH)        // 22
#define NSRC (WINX * WINY)      // 1012
#define TPB 256
#define MAXK 4                  // ceil(NSRC/TPB)
#define NCH 16                  // channels per chunk (bf16-staged)
#define NCHUNK (CC / NCH)       // 4 chunks, looped INSIDE the block
#define NCELLX (TX + 1)         // 33  (cells lx = -1..TX-1)
#define NCELLY (TY + 1)         // 9
#define NCELL (NCELLX * NCELLY) // 297
#define CAPC 8                  // per-cell list capacity (Poisson(1): P(>8)~1e-6)
#define CAP 448                 // compact-id capacity (mean ~330, +8 sigma)
#define OVCAP 64                // overflow side-list capacity

// pack two fp32 -> one u32 of 2x bf16 (RNE); lo -> bits[15:0], hi -> bits[31:16]
__device__ __forceinline__ unsigned pack_bf16(float lo, float hi) {
    __hip_bfloat162 h = __float22bfloat162_rn(float2{lo, hi});
    return *reinterpret_cast<unsigned*>(&h);
}

// ws layout (floats): [0, B*HW) = weight accumulator (outliers only);
//                     [B*HW]    = outlier flag (as u32)

// ---------------------------------------------------------------------------
// K1: detect any source pixel with |flow| > LOCAL_MAX (rare path trigger).
// ---------------------------------------------------------------------------
__global__ __launch_bounds__(TPB) void flag_kernel(
    const float* __restrict__ flow, unsigned* __restrict__ flag)
{
    int p = blockIdx.x * TPB + threadIdx.x;
    if (p >= BB * HW) return;
    int b = p / HW, rem = p - b * HW;
    float dx = flow[(b * 2 + 0) * HW + rem];
    float dy = flow[(b * 2 + 1) * HW + rem];
    if (!((fabsf(dx) <= LOCAL_MAX) && (fabsf(dy) <= LOCAL_MAX)))
        atomicOr(flag, 1u);
}

// ---------------------------------------------------------------------------
// K2: zero d_out only if outliers exist (they atomically accumulate into it).
// ---------------------------------------------------------------------------
__global__ __launch_bounds__(TPB) void cond_zero_kernel(
    float4* __restrict__ out4, const unsigned* __restrict__ flag)
{
    if (*flag == 0u) return;
    const int n4 = BB * CHW / 4;
    for (int i = blockIdx.x * TPB + threadIdx.x; i < n4; i += gridDim.x * TPB)
        out4[i] = float4{0.f, 0.f, 0.f, 0.f};
}

// ---------------------------------------------------------------------------
// K3: rare-path scatter for outlier sources (global atomics; ~0 pixels here).
// ---------------------------------------------------------------------------
__global__ __launch_bounds__(TPB) void outlier_kernel(
    const float* __restrict__ inp, const float* __restrict__ flow,
    const float* __restrict__ mask, float* __restrict__ acc,
    float* __restrict__ wacc, const unsigned* __restrict__ flag)
{
    if (*flag == 0u) return;
    int p = blockIdx.x * TPB + threadIdx.x;
    if (p >= BB * HW) return;
    int b = p / HW, rem = p - b * HW;
    int y = rem / WW, x = rem - y * WW;

    float dx = flow[(b * 2 + 0) * HW + rem];
    float dy = flow[(b * 2 + 1) * HW + rem];
    if ((fabsf(dx) <= LOCAL_MAX) && (fabsf(dy) <= LOCAL_MAX)) return;

    float tx = (float)x + dx, ty = (float)y + dy;
    float x0f = floorf(tx), y0f = floorf(ty);
    int   x0 = (int)x0f, y0 = (int)y0f;
    float fx = tx - x0f, fy = ty - y0f;
    float wx[2] = {1.0f - fx, fx};
    float wy[2] = {1.0f - fy, fy};
    float m = expf(mask[b * HW + rem]);

    int   cidx[4];
    float cw[4];
    bool  cv[4];
#pragma unroll
    for (int j = 0; j < 4; ++j) {
        int xi = x0 + (j & 1), yi = y0 + (j >> 1);
        cv[j]   = (xi >= 0) & (xi < WW) & (yi >= 0) & (yi < HH);
        cidx[j] = yi * WW + xi;
        cw[j]   = wx[j & 1] * wy[j >> 1] * m;
    }
    float* wbase = wacc + b * HW;
#pragma unroll
    for (int j = 0; j < 4; ++j)
        if (cv[j]) unsafeAtomicAdd(wbase + cidx[j], cw[j]);
    const float* ibase = inp + b * CHW + rem;
    float*       obase = acc + b * CHW;
    for (int c = 0; c < CC; ++c) {
        float v = ibase[c * HW];
#pragma unroll
        for (int j = 0; j < 4; ++j)
            if (cv[j]) unsafeAtomicAdd(obase + c * HW + cidx[j], cw[j] * v);
    }
}

// ---------------------------------------------------------------------------
// K4: atomic-free gather-splat; scan/bin once per tile; channel-chunk loop
// with register prefetch; XCD-aware block swizzle; bf16 w4 + u16 slot ids
// shrink LDS to ~25 KB -> HW residency 6 blocks/CU.
// NOTE: __launch_bounds__ 2nd arg = min waves/EU. 5 (cap ~102 VGPR) is the
// no-spill setting; forcing 6 made the allocator spill the prefetch arrays
// to scratch (+195 MB HBM writes, 2x slowdown) in R12.
// ---------------------------------------------------------------------------
__global__ __launch_bounds__(TPB, 5) void gather_kernel(
    const float* __restrict__ inp, const float* __restrict__ flow,
    const float* __restrict__ mask, float* __restrict__ out,
    const float* __restrict__ wacc, const unsigned* __restrict__ flag)
{
    __shared__ uint2          s_w4b[CAP];         // w4 as 2x (2x bf16): {j0,j1},{j2,j3}
    __shared__ unsigned short s_slot[CAP];        // window slot id (< NSRC)
    __shared__ uint4          s_vals[CAP * 2];    // 16 ch as 2xbf16 x8 (reused/chunk)
    __shared__ unsigned short s_list[NCELL * CAPC];
    __shared__ int            s_cnt[NCELL];
    __shared__ int            s_ovf[OVCAP];
    __shared__ int            s_ovfn, s_nc;

    // XCD-aware swizzle: consecutive same-XCD blocks get contiguous tile ids
    const int bid  = blockIdx.x;
    const int orig = (bid & 7) * (NWG / 8) + (bid >> 3);
    const int bxi  = orig % NTX;
    const int tmp  = orig / NTX;
    const int byi  = tmp & (NTY - 1);             // NTY = 32
    const int b    = tmp >> 5;

    const int bx0  = bxi * TX;
    const int by0  = byi * TY;
    const int tid  = threadIdx.x;
    const int lane = tid & 63;

    for (int i = tid; i < NCELL; i += TPB) s_cnt[i] = 0;
    if (tid == 0) { s_ovfn = 0; s_nc = 0; }
    __syncthreads();

    const float* __restrict__ fxp = flow + (b * 2 + 0) * HW;
    const float* __restrict__ fyp = flow + (b * 2 + 1) * HW;
    const float* __restrict__ mp  = mask + b * HW;

    // ---- Stage A: scan + compact + bin (ONCE per tile) -------------------
    for (int k = 0; k < MAXK; ++k) {
        const int s  = k * TPB + tid;
        const int sy = s / WINX;
        const int sx = s - sy * WINX;
        const int gx = bx0 - TH + sx;
        const int gy = by0 - TH + sy;
        bool pass = (s < NSRC) & (gx >= 0) & (gx < WW) & (gy >= 0) & (gy < HH);
        const int sp = gy * WW + gx;
        float dx = 0.f, dy = 0.f;
        if (pass) {
            dx = fxp[sp];
            dy = fyp[sp];
            pass = (fabsf(dx) <= LOCAL_MAX) && (fabsf(dy) <= LOCAL_MAX);
        }
        const float tx  = (float)gx + dx;
        const float ty  = (float)gy + dy;
        const float x0f = floorf(tx), y0f = floorf(ty);
        const int   lx  = (int)x0f - bx0;
        const int   ly  = (int)y0f - by0;
        pass = pass && (lx >= -1) && (lx < TX) && (ly >= -1) && (ly < TY);

        // wave-ballot compact-id allocation
        const unsigned long long ball = __ballot(pass);
        int base = 0;
        if (lane == 0) base = atomicAdd(&s_nc, (int)__popcll(ball));
        base = __shfl(base, 0);
        const int cid = base + (int)__popcll(ball & ((1ull << lane) - 1ull));

        if (!pass || cid >= CAP) continue;

        const float fx = tx - x0f, fy = ty - y0f;
        const float ox = 1.0f - fx, oy = 1.0f - fy;
        const float m  = expf(mp[sp]);
        // components ordered by jidx: {j0=ox*oy, j1=fx*oy}, {j2=ox*fy, j3=fx*fy}
        s_w4b[cid] = uint2{pack_bf16(ox * oy * m, fx * oy * m),
                           pack_bf16(ox * fy * m, fx * fy * m)};
        s_slot[cid] = (unsigned short)s;

        const int cellid = (ly + 1) * NCELLX + (lx + 1);
        const int pos = atomicAdd(&s_cnt[cellid], 1);
        if (pos < CAPC) {
            s_list[cellid * CAPC + pos] = (unsigned short)cid;
        } else {
            const int op = atomicAdd(&s_ovfn, 1);
            if (op < OVCAP) s_ovf[op] = cid | (cellid << 16);
        }
    }
    __syncthreads();

    // ---- per-pixel / per-thread constants cached across chunks -----------
    const int px = tid & 31, py = tid >> 5;        // 32x8 = 256 pixels, 1/thread
    const int c00 = min(s_cnt[(py + 0) * NCELLX + (px + 0)], CAPC);
    const int c10 = min(s_cnt[(py + 0) * NCELLX + (px + 1)], CAPC);
    const int c01 = min(s_cnt[(py + 1) * NCELLX + (px + 0)], CAPC);
    const int c11 = min(s_cnt[(py + 1) * NCELLX + (px + 1)], CAPC);
    const int t0 = c00, t1 = t0 + c10, t2 = t1 + c01, T = t2 + c11;
    const int nc   = min(s_nc, CAP);
    const int novf = min(s_ovfn, OVCAP);
    const int gpix = (by0 + py) * WW + (bx0 + px);
    const bool has_out = (*flag != 0u);
    const unsigned* __restrict__ w4w = (const unsigned*)s_w4b;

    // staging sources owned by this thread (slot -> global pixel, recomputed)
    const bool h0 = tid < nc, h1 = tid + TPB < nc;
    int sp0 = 0, sp1 = 0;
    {
        const int s0 = h0 ? (int)s_slot[tid] : 0;
        const int s1 = h1 ? (int)s_slot[tid + TPB] : 0;
        const int sy0 = s0 / WINX, sy1 = s1 / WINX;
        sp0 = (by0 - TH + sy0) * WW + (bx0 - TH + (s0 - sy0 * WINX));
        sp1 = (by0 - TH + sy1) * WW + (bx0 - TH + (s1 - sy1 * WINX));
    }

    // ---- preload chunk 0 into registers ----------------------------------
    float v0[NCH], v1[NCH];
    {
        const float* __restrict__ ib = inp + b * CC * HW;
#pragma unroll
        for (int c = 0; c < NCH; ++c) {
            v0[c] = h0 ? ib[c * HW + sp0] : 0.f;
            v1[c] = h1 ? ib[c * HW + sp1] : 0.f;
        }
    }
    unsigned pk0[8], pk1[8];
#pragma unroll
    for (int q = 0; q < 8; ++q) {
        pk0[q] = pack_bf16(v0[2 * q], v0[2 * q + 1]);
        pk1[q] = pack_bf16(v1[2 * q], v1[2 * q + 1]);
    }

    float rden = 0.f;   // set in chunk 0

    // ---- chunk loop: write LDS, prefetch next, gather, pack --------------
    for (int g = 0; g < NCHUNK; ++g) {
        if (h0) {
            s_vals[tid * 2 + 0] = uint4{pk0[0], pk0[1], pk0[2], pk0[3]};
            s_vals[tid * 2 + 1] = uint4{pk0[4], pk0[5], pk0[6], pk0[7]};
        }
        if (h1) {
            s_vals[(tid + TPB) * 2 + 0] = uint4{pk1[0], pk1[1], pk1[2], pk1[3]};
            s_vals[(tid + TPB) * 2 + 1] = uint4{pk1[4], pk1[5], pk1[6], pk1[7]};
        }
        __syncthreads();

        // issue next chunk's global loads NOW; consumed after the gather
        if (g + 1 < NCHUNK) {
            const float* __restrict__ ibn = inp + (b * CC + (g + 1) * NCH) * HW;
#pragma unroll
            for (int c = 0; c < NCH; ++c) {
                v0[c] = h0 ? ibn[c * HW + sp0] : 0.f;
                v1[c] = h1 ? ibn[c * HW + sp1] : 0.f;
            }
        }

        // ---- gather chunk g from LDS ------------------------------------
        float wsum = 0.f;
        float2 a2[8];
#pragma unroll
        for (int q = 0; q < 8; ++q) a2[q] = float2{0.f, 0.f};

        for (int k = 0; k < T; ++k) {
            int d, e, ci;
            if (k < t1) { e = 0; d = (k >= t0); ci = d ? (k - t0) : k; }
            else        { e = 1; d = (k >= t2); ci = d ? (k - t2) : (k - t1); }
            const int cellid = (py + e) * NCELLX + (px + d);
            const int cid    = s_list[cellid * CAPC + ci];
            // w component jidx = (1-d) + 2*(1-e): u32 index (1-e), hi-half if d==0
            const unsigned wb = w4w[cid * 2 + (e ^ 1)];
            const float w = __uint_as_float(d ? (wb << 16) : (wb & 0xffff0000u));
            wsum += w;
            const uint4 q0 = s_vals[cid * 2 + 0];
            const uint4 q1 = s_vals[cid * 2 + 1];
            const unsigned uu[8] = {q0.x, q0.y, q0.z, q0.w, q1.x, q1.y, q1.z, q1.w};
#pragma unroll
            for (int q = 0; q < 8; ++q) {
                a2[q].x += w * __uint_as_float(uu[q] << 16);
                a2[q].y += w * __uint_as_float(uu[q] & 0xffff0000u);
            }
        }

        // rare overflow entries (exact handling)
        for (int i = 0; i < novf; ++i) {
            const int ent    = s_ovf[i];
            const int cid    = ent & 0xffff;
            const int cellid = ent >> 16;
            const int cy = cellid / NCELLX, cx = cellid - cy * NCELLX;
            const int jx = px - (cx - 1), jy = py - (cy - 1);
            if ((unsigned)jx <= 1u && (unsigned)jy <= 1u) {
                const unsigned wb = w4w[cid * 2 + jy];
                const float w = __uint_as_float(jx ? (wb & 0xffff0000u) : (wb << 16));
                wsum += w;
                const uint4 q0 = s_vals[cid * 2 + 0];
                const uint4 q1 = s_vals[cid * 2 + 1];
                const unsigned uu[8] = {q0.x, q0.y, q0.z, q0.w, q1.x, q1.y, q1.z, q1.w};
#pragma unroll
                for (int q = 0; q < 8; ++q) {
                    a2[q].x += w * __uint_as_float(uu[q] << 16);
                    a2[q].y += w * __uint_as_float(uu[q] & 0xffff0000u);
                }
            }
        }

        if (g == 0)
            rden = 1.0f / (wsum + wacc[b * HW + gpix] + 1e-7f);

        const int obase = (b * CC + g * NCH) * HW;
#pragma unroll
        for (int q = 0; q < 8; ++q) {
            const int gi0 = obase + (2 * q + 0) * HW + gpix;
            const int gi1 = obase + (2 * q + 1) * HW + gpix;
            float av0 = a2[q].x, av1 = a2[q].y;
            if (has_out) { av0 += out[gi0]; av1 += out[gi1]; }
            out[gi0] = av0 * rden;
            out[gi1] = av1 * rden;
        }

        // pack next chunk (vmcnt waits land here, after the gather)
        if (g + 1 < NCHUNK) {
#pragma unroll
            for (int q = 0; q < 8; ++q) {
                pk0[q] = pack_bf16(v0[2 * q], v0[2 * q + 1]);
                pk1[q] = pack_bf16(v1[2 * q], v1[2 * q + 1]);
            }
            __syncthreads();       // all gathers done before s_vals overwrite
        }
    }
}

extern "C" void kernel_launch(void* const* d_in, const int* in_sizes, int n_in,
                              void* d_out, int out_size, void* d_ws, size_t ws_size,
                              hipStream_t stream) {
    const float* inp  = (const float*)d_in[0];  // [4,64,256,448]
    const float* flow = (const float*)d_in[1];  // [4,2,256,448]
    const float* mask = (const float*)d_in[2];  // [4,1,256,448]
    float*    out  = (float*)d_out;
    float*    wacc = (float*)d_ws;                          // [B,HW] outlier weights
    unsigned* flag = (unsigned*)((float*)d_ws + BB * HW);   // outlier flag

    // zero wacc + flag every call (deterministic under graph replay)
    hipMemsetAsync(d_ws, 0, (size_t)(BB * HW + 4) * sizeof(float), stream);

    const int npix = BB * HW;
    flag_kernel<<<(npix + TPB - 1) / TPB, TPB, 0, stream>>>(flow, flag);
    cond_zero_kernel<<<2048, TPB, 0, stream>>>((float4*)out, flag);
    outlier_kernel<<<(npix + TPB - 1) / TPB, TPB, 0, stream>>>(inp, flow, mask, out, wacc, flag);
    gather_kernel<<<NWG, TPB, 0, stream>>>(inp, flow, mask, out, wacc, flag);
}